// Round 4
// baseline (3841.319 us; speedup 1.0000x reference)
//
#include <hip/hip_runtime.h>
#include <hip/hip_bf16.h>

typedef unsigned short u16;
using short8 = __attribute__((ext_vector_type(8))) short;
using f32x4  = __attribute__((ext_vector_type(4))) float;

#define DEVINL static __device__ __forceinline__

DEVINL float bf2f(u16 u){
  union { unsigned int i; float f; } x; x.i = ((unsigned int)u) << 16; return x.f;
}
DEVINL u16 f2bf(float f){
  union { float f; unsigned int i; } x; x.f = f;
  unsigned int i = x.i;
  return (u16)((i + 0x7FFFu + ((i >> 16) & 1u)) >> 16);
}
DEVINL float sigm(float x){ return 1.f / (1.f + __expf(-x)); }
DEVINL float tanhf_(float x){
  x = fminf(fmaxf(x, -20.f), 20.f);
  float e = __expf(-2.f * x);
  return (1.f - e) / (1.f + e);
}
DEVINL f32x4 zero4(){ f32x4 z = {0.f, 0.f, 0.f, 0.f}; return z; }

DEVINL f32x4 mfma16(short8 a, short8 b, f32x4 c){
  return __builtin_amdgcn_mfma_f32_16x16x32_bf16(a, b, c, 0, 0, 0);
}

// lane l: row = l&15, k0 = (l>>4)*8 ; 16B vector read. stride in u16 elements (rows 16B-aligned)
DEVINL short8 frag_ld(const u16* base, int stride){
  int l = threadIdx.x & 63;
  return *(const short8*)(base + (l & 15) * stride + ((l >> 4) << 3));
}
// fragment load directly from global, row stride in u16, ks selects 32-col K slice
DEVINL short8 gfrag(const u16* rowbase, int stride, int ks){
  int l = threadIdx.x & 63;
  return *(const short8*)(rowbase + (size_t)(l & 15) * stride + ks * 32 + ((l >> 4) << 3));
}

// acc layout: col = lane&15 (+col_base), rows = (lane>>4)*4 + r
DEVINL void acc_store_lds(u16* dst, int stride, int col_base, f32x4 acc, float bias, bool relu){
  int l = threadIdx.x & 63;
  int col = col_base + (l & 15);
  int row0 = (l >> 4) * 4;
  #pragma unroll
  for (int r = 0; r < 4; r++){
    float v = acc[r] + bias;
    if (relu) v = fmaxf(v, 0.f);
    dst[(row0 + r) * stride + col] = f2bf(v);
  }
}

// stage fp32 (N,K) row-major weights -> bf16 LDS [N][Kp+8]; zero cols K..Kp
DEVINL void stage_weights(u16* dst, const float* src, int N, int K, int Kp){
  int stride = Kp + 8;
  if (Kp > K){
    int padw = Kp - K;
    for (int i = threadIdx.x; i < N * padw; i += blockDim.x){
      int n = i / padw, k = K + (i - (i / padw) * padw);
      dst[n * stride + k] = 0;
    }
  }
  for (int i = threadIdx.x * 4; i < N * K; i += blockDim.x * 4){
    float4 v = *(const float4*)(src + i);
    int n = i / K, k = i - n * K;
    u16* d = dst + n * stride + k;
    d[0] = f2bf(v.x); d[1] = f2bf(v.y); d[2] = f2bf(v.z); d[3] = f2bf(v.w);
  }
}

__global__ __launch_bounds__(256) void k_inith(const float* __restrict__ h0, u16* __restrict__ hst){
  int i = blockIdx.x * 256 + threadIdx.x;
  if (i < 2 * 1024 * 128) hst[i] = f2bf(h0[i]);
}

// ---------------- phase A: phi_u, per-wave independent tiles, no inner barriers ----------------
__global__ __launch_bounds__(512, 4) void k_phiu(const float* __restrict__ u,
    const float* __restrict__ w0, const float* __restrict__ b0,
    const float* __restrict__ w1, const float* __restrict__ b1,
    u16* __restrict__ phi, int t0, int Tc){
  __shared__ __align__(16) u16 w0s[128 * 40];
  __shared__ __align__(16) u16 w1s[128 * 136];
  __shared__ __align__(16) u16 buf[8][16 * 136];
  stage_weights(w0s, w0, 128, 16, 32);
  stage_weights(w1s, w1, 128, 128, 128);
  int wv = threadIdx.x >> 6, l = threadIdx.x & 63;
  u16* mybuf = buf[wv];
  float b0v[8], b1v[8];
  #pragma unroll
  for (int nt = 0; nt < 8; nt++){
    b0v[nt] = b0[nt * 16 + (l & 15)];
    b1v[nt] = b1[nt * 16 + (l & 15)];
  }
  __syncthreads();
  int tpb = Tc >> 4;
  int ntile = 1024 * tpb;
  int stride = gridDim.x * 8;
  for (int tile = blockIdx.x * 8 + wv; tile < ntile; tile += stride){
    int b = tile / tpb;
    int tt = (tile - b * tpb) << 4;
    int t = l & 15, kb = l >> 4;
    #pragma unroll
    for (int j = 0; j < 4; j++){
      int k = kb + j * 4;
      mybuf[t * 136 + k] = f2bf(u[(size_t)(b * 16 + k) * 1024 + t0 + tt + t]);
      mybuf[t * 136 + 16 + k] = 0;
    }
    short8 a0 = frag_ld(mybuf, 136);
    f32x4 acc[8];
    #pragma unroll
    for (int nt = 0; nt < 8; nt++)
      acc[nt] = mfma16(a0, frag_ld(w0s + nt * 16 * 40, 40), zero4());
    #pragma unroll
    for (int nt = 0; nt < 8; nt++)
      acc_store_lds(mybuf, 136, nt * 16, acc[nt], b0v[nt], true);
    f32x4 a2[8];
    #pragma unroll
    for (int nt = 0; nt < 8; nt++) a2[nt] = zero4();
    #pragma unroll
    for (int ks = 0; ks < 4; ks++){
      short8 a = frag_ld(mybuf + ks * 32, 136);
      #pragma unroll
      for (int nt = 0; nt < 8; nt++)
        a2[nt] = mfma16(a, frag_ld(w1s + nt * 16 * 136 + ks * 32, 136), a2[nt]);
    }
    #pragma unroll
    for (int nt = 0; nt < 8; nt++)
      acc_store_lds(mybuf, 136, nt * 16, a2[nt], b1v[nt], false);
    u16* dst = phi + (size_t)(b * Tc + tt) * 128;
    #pragma unroll
    for (int j = 0; j < 4; j++){
      int c = j * 64 + l;
      int row = c >> 4, k = (c & 15) * 8;
      *(short8*)(dst + row * 128 + k) = *(const short8*)(mybuf + row * 136 + k);
    }
  }
}

// ---------------- phase B: 2-layer GRU, layer-pipelined, 1 barrier/step ----------------
// Fragment-major LDS tiles: per 16x128 tile, slice ks (32 cols) stored as 64 lane-slots
// of 8 u16: elem(row,col) -> ks=col>>5, lane = row + (((col>>3)&3)<<4), e = col&7.
// A-fragment read for lane l is then the contiguous 16B at ks*512 + l*8 (conflict-free).
__global__ __launch_bounds__(512, 1) void k_gru(const u16* __restrict__ phi,
    const float* __restrict__ gwih, const float* __restrict__ gwhh,
    u16* __restrict__ hst, u16* __restrict__ Hs, int Tc){
  __shared__ __align__(16) u16 h0s[2][2048];
  __shared__ __align__(16) u16 h1s[2][2048];
  int wv = threadIdx.x >> 6, l = threadIdx.x & 63;
  int b0 = blockIdx.x * 16;
  int m0 = (l >> 4) * 4;
  int colw = wv * 16 + (l & 15);
  // owner-write base in fragment-major layout (4 writes at +r*8)
  int wbase = (colw >> 5) * 512 + (m0 + (((colw >> 3) & 3) << 4)) * 8 + (colw & 7);

  // stationary register weights: wih0, whh0, wih1, whh1 — 12 short8 (48 VGPR) each
  const float* srcs[4] = { gwih, gwhh, gwih + 49152, gwhh + 49152 };
  short8 W[4][3][4];
  #pragma unroll
  for (int mm = 0; mm < 4; mm++){
    #pragma unroll
    for (int g = 0; g < 3; g++){
      int n = g * 128 + colw;
      #pragma unroll
      for (int ks = 0; ks < 4; ks++){
        const float* p = srcs[mm] + (size_t)n * 128 + ks * 32 + ((l >> 4) << 3);
        float4 va = *(const float4*)p;
        float4 vb = *(const float4*)(p + 4);
        short8 f;
        f[0] = (short)f2bf(va.x); f[1] = (short)f2bf(va.y);
        f[2] = (short)f2bf(va.z); f[3] = (short)f2bf(va.w);
        f[4] = (short)f2bf(vb.x); f[5] = (short)f2bf(vb.y);
        f[6] = (short)f2bf(vb.z); f[7] = (short)f2bf(vb.w);
        W[mm][g][ks] = f;
      }
    }
  }
  // restore state: hst row-major -> fragment-major LDS (thread i: row=i>>5, k0=(i&31)*4)
  {
    int row = threadIdx.x >> 5, k0 = (threadIdx.x & 31) * 4;
    int ks = k0 >> 5, lane = row + (((k0 >> 3) & 3) << 4), e = k0 & 7;
    *(uint2*)(&h0s[0][ks * 512 + lane * 8 + e]) =
        *(const uint2*)(hst + (size_t)(b0 + row) * 128 + k0);
    *(uint2*)(&h1s[0][ks * 512 + lane * 8 + e]) =
        *(const uint2*)(hst + 131072 + (size_t)(b0 + row) * 128 + k0);
  }
  float h0reg[4], h1reg[4];
  #pragma unroll
  for (int r = 0; r < 4; r++){
    h0reg[r] = bf2f(hst[(size_t)(b0 + m0 + r) * 128 + colw]);
    h1reg[r] = bf2f(hst[131072 + (size_t)(b0 + m0 + r) * 128 + colw]);
  }
  // phi A-fragment prefetch for t=0 (direct from global; L2-resident)
  short8 pf[4];
  #pragma unroll
  for (int ks = 0; ks < 4; ks++)
    pf[ks] = *(const short8*)(phi + ((size_t)(b0 + (l & 15)) * Tc) * 128 + ks * 32 + ((l >> 4) << 3));
  __syncthreads();

  // iteration i: layer0 computes H0[i+1]=f(H0[i],phi(i)) [if i<Tc];
  //             layer1 computes H1[i]=f(H1[i-1],H0[i])   [if i>0].
  // Both read only state published at the previous barrier; gh0/gi1 share a0 = H0[i].
  auto ITER = [&](int i, int P){
    short8 a0[4], a1[4];
    #pragma unroll
    for (int ks = 0; ks < 4; ks++)
      a0[ks] = *(const short8*)(&h0s[P][ks * 512 + l * 8]);
    if (i > 0){
      #pragma unroll
      for (int ks = 0; ks < 4; ks++)
        a1[ks] = *(const short8*)(&h1s[P ^ 1][ks * 512 + l * 8]);
      // Hs(i-1) <- H1[i-1] (stable buffer this iteration), coalesced 256B/row segments
      {
        int row = threadIdx.x >> 5, k0 = (threadIdx.x & 31) * 4;
        int ks = k0 >> 5, lane = row + (((k0 >> 3) & 3) << 4);
        uint2 v = *(const uint2*)(&h1s[P ^ 1][ks * 512 + lane * 8 + (k0 & 7)]);
        *(uint2*)(Hs + ((size_t)(b0 + row) * Tc + (i - 1)) * 128 + k0) = v;
      }
      // layer 1
      f32x4 cr = zero4(), cz = zero4(), cin = zero4(), chn = zero4();
      #pragma unroll
      for (int ks = 0; ks < 4; ks++){
        cr  = mfma16(a0[ks], W[2][0][ks], cr);
        cz  = mfma16(a0[ks], W[2][1][ks], cz);
        cin = mfma16(a0[ks], W[2][2][ks], cin);
        cr  = mfma16(a1[ks], W[3][0][ks], cr);
        cz  = mfma16(a1[ks], W[3][1][ks], cz);
        chn = mfma16(a1[ks], W[3][2][ks], chn);
      }
      #pragma unroll
      for (int r = 0; r < 4; r++){
        float rg = sigm(cr[r]);
        float zg = sigm(cz[r]);
        float ng = tanhf_(cin[r] + rg * chn[r]);
        float hn = (1.f - zg) * ng + zg * h1reg[r];
        h1reg[r] = hn;
        h1s[P][wbase + r * 8] = f2bf(hn);
      }
    }
    if (i < Tc){
      // layer 0
      f32x4 cr = zero4(), cz = zero4(), cin = zero4(), chn = zero4();
      #pragma unroll
      for (int ks = 0; ks < 4; ks++){
        cr  = mfma16(pf[ks], W[0][0][ks], cr);
        cz  = mfma16(pf[ks], W[0][1][ks], cz);
        cin = mfma16(pf[ks], W[0][2][ks], cin);
        cr  = mfma16(a0[ks], W[1][0][ks], cr);
        cz  = mfma16(a0[ks], W[1][1][ks], cz);
        chn = mfma16(a0[ks], W[1][2][ks], chn);
      }
      #pragma unroll
      for (int r = 0; r < 4; r++){
        float rg = sigm(cr[r]);
        float zg = sigm(cz[r]);
        float ng = tanhf_(cin[r] + rg * chn[r]);
        float hn = (1.f - zg) * ng + zg * h0reg[r];
        h0reg[r] = hn;
        h0s[P ^ 1][wbase + r * 8] = f2bf(hn);
      }
      // prefetch phi(i+1) fragments (used next iteration; vmcnt waited at use)
      if (i + 1 < Tc){
        #pragma unroll
        for (int ks = 0; ks < 4; ks++)
          pf[ks] = *(const short8*)(phi + ((size_t)(b0 + (l & 15)) * Tc + (i + 1)) * 128
                                    + ks * 32 + ((l >> 4) << 3));
      }
    }
    asm volatile("s_waitcnt lgkmcnt(0)" ::: "memory");
    __builtin_amdgcn_s_barrier();
    asm volatile("" ::: "memory");
  };

  ITER(0, 0);
  for (int i = 1; i < Tc; i += 2){
    ITER(i, 1);
    ITER(i + 1, 0);
  }
  // save state: Tc even -> H0[Tc] in h0s[0], H1[Tc] in h1s[0]
  {
    int row = threadIdx.x >> 5, k0 = (threadIdx.x & 31) * 4;
    int ks = k0 >> 5, lane = row + (((k0 >> 3) & 3) << 4), e = k0 & 7;
    *(uint2*)(hst + (size_t)(b0 + row) * 128 + k0) =
        *(const uint2*)(&h0s[0][ks * 512 + lane * 8 + e]);
    *(uint2*)(hst + 131072 + (size_t)(b0 + row) * 128 + k0) =
        *(const uint2*)(&h1s[0][ks * 512 + lane * 8 + e]);
  }
}

// ---------------- phase C1: dynn + x_mean/x_logvar, per-wave tiles ----------------
__global__ __launch_bounds__(512, 2) void k_c1(const u16* __restrict__ phi, const u16* __restrict__ Hs,
    const float* __restrict__ dw0, const float* __restrict__ db0,
    const float* __restrict__ dw1, const float* __restrict__ db1,
    const float* __restrict__ xmw, const float* __restrict__ xmb,
    const float* __restrict__ xlw, const float* __restrict__ xlb,
    u16* __restrict__ xmlv, int Tc){
  __shared__ __align__(16) u16 w0s[128 * 264];
  __shared__ __align__(16) u16 w1s[128 * 136];
  __shared__ __align__(16) u16 xws[32 * 136];
  __shared__ __align__(16) u16 buf[8][16 * 136];
  stage_weights(w0s, dw0, 128, 256, 256);
  stage_weights(w1s, dw1, 128, 128, 128);
  stage_weights(xws, xmw, 16, 128, 128);
  stage_weights(xws + 16 * 136, xlw, 16, 128, 128);
  int wv = threadIdx.x >> 6, l = threadIdx.x & 63;
  u16* mybuf = buf[wv];
  float b0v[8], b1v[8];
  #pragma unroll
  for (int nt = 0; nt < 8; nt++){
    b0v[nt] = db0[nt * 16 + (l & 15)];
    b1v[nt] = db1[nt * 16 + (l & 15)];
  }
  float bxm = xmb[l & 15], bxl = xlb[l & 15];
  __syncthreads();
  int tpb = Tc >> 4;
  int ntile = 1024 * tpb;
  int stride = gridDim.x * 8;
  for (int tile = blockIdx.x * 8 + wv; tile < ntile; tile += stride){
    int b = tile / tpb;
    int tt = (tile - b * tpb) << 4;
    size_t rbase = (size_t)(b * Tc + tt);
    const u16* ap = phi + rbase * 128;
    const u16* hp = Hs + rbase * 128;
    f32x4 acc[8];
    #pragma unroll
    for (int nt = 0; nt < 8; nt++) acc[nt] = zero4();
    #pragma unroll
    for (int ks = 0; ks < 8; ks++){
      short8 a = (ks < 4) ? gfrag(ap, 128, ks) : gfrag(hp, 128, ks - 4);
      #pragma unroll
      for (int nt = 0; nt < 8; nt++)
        acc[nt] = mfma16(a, frag_ld(w0s + nt * 16 * 264 + ks * 32, 264), acc[nt]);
    }
    #pragma unroll
    for (int nt = 0; nt < 8; nt++)
      acc_store_lds(mybuf, 136, nt * 16, acc[nt], b0v[nt], true);
    f32x4 a2[8];
    #pragma unroll
    for (int nt = 0; nt < 8; nt++) a2[nt] = zero4();
    #pragma unroll
    for (int ks = 0; ks < 4; ks++){
      short8 a = frag_ld(mybuf + ks * 32, 136);
      #pragma unroll
      for (int nt = 0; nt < 8; nt++)
        a2[nt] = mfma16(a, frag_ld(w1s + nt * 16 * 136 + ks * 32, 136), a2[nt]);
    }
    #pragma unroll
    for (int nt = 0; nt < 8; nt++)
      acc_store_lds(mybuf, 136, nt * 16, a2[nt], b1v[nt], false);
    f32x4 am = zero4(), al = zero4();
    #pragma unroll
    for (int ks = 0; ks < 4; ks++){
      short8 a = frag_ld(mybuf + ks * 32, 136);
      am = mfma16(a, frag_ld(xws + ks * 32, 136), am);
      al = mfma16(a, frag_ld(xws + 16 * 136 + ks * 32, 136), al);
    }
    acc_store_lds(mybuf, 136, 0, am, bxm, false);
    acc_store_lds(mybuf, 136, 16, al, bxl, false);
    u16* dst = xmlv + rbase * 32;
    int c = l;
    int row = c >> 2, k = (c & 3) * 8;
    *(short8*)(dst + row * 32 + k) = *(const short8*)(mybuf + row * 136 + k);
  }
}

// ---------------- phase C2: phi_x + menn + C@x_mean + loss, per-wave tiles ----------------
__global__ __launch_bounds__(512, 2) void k_c2(const u16* __restrict__ xmlv, const float* __restrict__ y,
    const float* __restrict__ pw0, const float* __restrict__ pb0,
    const float* __restrict__ pw1, const float* __restrict__ pb1,
    const float* __restrict__ mw0, const float* __restrict__ mb0,
    const float* __restrict__ mw1, const float* __restrict__ mb1,
    const float* __restrict__ Cw, float* __restrict__ out, int t0, int Tc){
  __shared__ __align__(16) u16 pw0s[128 * 40];
  __shared__ __align__(16) u16 pw1s[128 * 136];
  __shared__ __align__(16) u16 mw0s[128 * 136];
  __shared__ __align__(16) u16 mw1s[16 * 136];
  __shared__ __align__(16) u16 Cs[16 * 40];
  __shared__ __align__(16) u16 buf[8][16 * 136];
  stage_weights(pw0s, pw0, 128, 32, 32);
  stage_weights(pw1s, pw1, 128, 128, 128);
  stage_weights(mw0s, mw0, 128, 128, 128);
  stage_weights(mw1s, mw1, 16, 128, 128);
  stage_weights(Cs, Cw, 16, 16, 32);
  int wv = threadIdx.x >> 6, l = threadIdx.x & 63;
  u16* mybuf = buf[wv];
  float bp0v[8], bp1v[8], bm0v[8];
  #pragma unroll
  for (int nt = 0; nt < 8; nt++){
    bp0v[nt] = pb0[nt * 16 + (l & 15)];
    bp1v[nt] = pb1[nt * 16 + (l & 15)];
    bm0v[nt] = mb0[nt * 16 + (l & 15)];
  }
  float bm1 = mb1[l & 15];
  __syncthreads();
  float lacc = 0.f;
  int tpb = Tc >> 4;
  int ntile = 1024 * tpb;
  int stride = gridDim.x * 8;
  for (int tile = blockIdx.x * 8 + wv; tile < ntile; tile += stride){
    int b = tile / tpb;
    int tt = (tile - b * tpb) << 4;
    size_t rbase = (size_t)(b * Tc + tt);
    const u16* xp = xmlv + rbase * 32;
    short8 a0 = gfrag(xp, 32, 0);
    f32x4 acc[8];
    #pragma unroll
    for (int nt = 0; nt < 8; nt++)
      acc[nt] = mfma16(a0, frag_ld(pw0s + nt * 16 * 40, 40), zero4());
    #pragma unroll
    for (int nt = 0; nt < 8; nt++)
      acc_store_lds(mybuf, 136, nt * 16, acc[nt], bp0v[nt], true);
    f32x4 a2[8];
    #pragma unroll
    for (int nt = 0; nt < 8; nt++) a2[nt] = zero4();
    #pragma unroll
    for (int ks = 0; ks < 4; ks++){
      short8 a = frag_ld(mybuf + ks * 32, 136);
      #pragma unroll
      for (int nt = 0; nt < 8; nt++)
        a2[nt] = mfma16(a, frag_ld(pw1s + nt * 16 * 136 + ks * 32, 136), a2[nt]);
    }
    #pragma unroll
    for (int nt = 0; nt < 8; nt++)
      acc_store_lds(mybuf, 136, nt * 16, a2[nt], bp1v[nt], false);
    f32x4 a3[8];
    #pragma unroll
    for (int nt = 0; nt < 8; nt++) a3[nt] = zero4();
    #pragma unroll
    for (int ks = 0; ks < 4; ks++){
      short8 a = frag_ld(mybuf + ks * 32, 136);
      #pragma unroll
      for (int nt = 0; nt < 8; nt++)
        a3[nt] = mfma16(a, frag_ld(mw0s + nt * 16 * 136 + ks * 32, 136), a3[nt]);
    }
    #pragma unroll
    for (int nt = 0; nt < 8; nt++)
      acc_store_lds(mybuf, 136, nt * 16, a3[nt], bm0v[nt], true);
    f32x4 ay = zero4();
    #pragma unroll
    for (int ks = 0; ks < 4; ks++){
      short8 a = frag_ld(mybuf + ks * 32, 136);
      ay = mfma16(a, frag_ld(mw1s + ks * 32, 136), ay);
    }
    f32x4 ac = mfma16(a0, frag_ld(Cs, 40), zero4());
    #pragma unroll
    for (int r = 0; r < 4; r++){
      float yh = ay[r] + bm1 + ac[r];
      int m = (l >> 4) * 4 + r, j = l & 15;
      float d = yh - y[(size_t)(b * 16 + j) * 1024 + t0 + tt + m];
      lacc += d * d;
    }
  }
  #pragma unroll
  for (int off = 32; off > 0; off >>= 1)
    lacc += __shfl_down(lacc, off);
  if (l == 0) atomicAdd(out, lacc);
}

extern "C" void kernel_launch(void* const* d_in, const int* in_sizes, int n_in,
                              void* d_out, int out_size, void* d_ws, size_t ws_size,
                              hipStream_t stream){
  const float* u    = (const float*)d_in[0];
  const float* y    = (const float*)d_in[1];
  const float* h0   = (const float*)d_in[2];
  const float* puw0 = (const float*)d_in[3];
  const float* pub0 = (const float*)d_in[4];
  const float* puw1 = (const float*)d_in[5];
  const float* pub1 = (const float*)d_in[6];
  const float* dw0  = (const float*)d_in[7];
  const float* db0  = (const float*)d_in[8];
  const float* dw1  = (const float*)d_in[9];
  const float* db1  = (const float*)d_in[10];
  const float* xmw  = (const float*)d_in[11];
  const float* xmb  = (const float*)d_in[12];
  const float* xlw  = (const float*)d_in[13];
  const float* xlb  = (const float*)d_in[14];
  const float* pxw0 = (const float*)d_in[15];
  const float* pxb0 = (const float*)d_in[16];
  const float* pxw1 = (const float*)d_in[17];
  const float* pxb1 = (const float*)d_in[18];
  const float* mw0  = (const float*)d_in[19];
  const float* mb0  = (const float*)d_in[20];
  const float* mw1  = (const float*)d_in[21];
  const float* mb1  = (const float*)d_in[22];
  const float* gwih = (const float*)d_in[23];
  const float* gwhh = (const float*)d_in[24];
  const float* Cw   = (const float*)d_in[25];

  char* w = (char*)d_ws;
  u16* hst = (u16*)w; w += (size_t)2 * 1024 * 128 * 2;
  size_t head = (size_t)2 * 1024 * 128 * 2 + 4096;
  size_t avail = (ws_size > head) ? (ws_size - head) : 0;
  int Tc = 1024;
  while (Tc > 64 && (size_t)1024 * (size_t)Tc * (128 + 128 + 32) * 2 > avail) Tc >>= 1;
  u16* phi  = (u16*)w; w += (size_t)1024 * Tc * 128 * 2;
  u16* Hs   = (u16*)w; w += (size_t)1024 * Tc * 128 * 2;
  u16* xmlv = (u16*)w; w += (size_t)1024 * Tc * 32 * 2;

  hipMemsetAsync(d_out, 0, sizeof(float), stream);
  k_inith<<<1024, 256, 0, stream>>>(h0, hst);
  for (int t0 = 0; t0 < 1024; t0 += Tc){
    k_phiu<<<512, 512, 0, stream>>>(u, puw0, pub0, puw1, pub1, phi, t0, Tc);
    k_gru<<<64, 512, 0, stream>>>(phi, gwih, gwhh, hst, Hs, Tc);
    k_c1<<<256, 512, 0, stream>>>(phi, Hs, dw0, db0, dw1, db1, xmw, xmb, xlw, xlb, xmlv, Tc);
    k_c2<<<256, 512, 0, stream>>>(xmlv, y, pxw0, pxb0, pxw1, pxb1, mw0, mb0, mw1, mb1, Cw,
                                  (float*)d_out, t0, Tc);
  }
}